// Round 11
// baseline (419.931 us; speedup 1.0000x reference)
//
#include <hip/hip_runtime.h>
#include <math.h>

#define Bdim 16
#define Mdim 4096
#define Tdim 4
#define Ddim 256
#define Vdim 40000
#define CONVMAX 512

// dot (D = tab . uf) tiling
#define DOT_VT 64
#define DOT_TILES (Vdim / DOT_VT)               // 625
#define DOT_KC 64
#define HD_JPB 32
#define HD_TILES (Bdim * (CONVMAX / HD_JPB))    // 256
// logit tiling
#define LG_TILES (Bdim * Mdim / 256)            // 256  (16 per b)
#define ZW_BLOCKS (Vdim * Bdim / 1024)          // 625
#define PW_BLOCKS (Bdim * CONVMAX / 1024)       // 8
// wsum tiling
#define WS_VT 100
#define WS_TILES (Vdim / WS_VT)                 // 400
#define WH_JPB 64
#define WH_TILES (Bdim * (CONVMAX / WH_JPB))    // 128
// reduce tiling
#define UF_CH 8
#define UF_PER (WS_TILES / UF_CH)               // 50
// att tiling
#define MT 64
#define ATT_CH (Mdim / MT)                      // 64
#define ATT_TILES (Bdim * ATT_CH)               // 1024

typedef float f32x4 __attribute__((ext_vector_type(4)));
static __device__ inline void nt_store4(float* p, float4 v) {
    f32x4 x = {v.x, v.y, v.z, v.w};
    __builtin_nontemporal_store(x, (f32x4*)p);
}
static __device__ inline void nt_store1(float* p, float v) {
    __builtin_nontemporal_store(v, p);
}

// combine per-b softmax partials (16 blocks of 256 rows each)
static __device__ inline void combine_stats(const float* __restrict__ blockmax,
                                            const float* __restrict__ blocksum,
                                            int b, float* M_out, float* rs_out) {
    float M = -INFINITY;
#pragma unroll
    for (int jj = 0; jj < 16; ++jj) M = fmaxf(M, blockmax[b * 16 + jj]);
    float S = 0.f;
#pragma unroll
    for (int jj = 0; jj < 16; ++jj) S += blocksum[b * 16 + jj] * expf(blockmax[b * 16 + jj] - M);
    *M_out = M;
    *rs_out = 1.0f / S;
}

// ---------------------------------------------------------------------------
// dot: D[v*16+b] = tab[v,:].uf[b,:]  (GEMM microtile) + Hdot
//      [+ init blocks: uf_out = qv, folded into the dot0 launch]
// grid: DOT_TILES + HD_TILES [+ init] blocks, 256 threads
// ---------------------------------------------------------------------------
__global__ void dot_kernel(const float* __restrict__ tab, const float* __restrict__ uf,
                           const float* __restrict__ hist,
                           float* __restrict__ D, float* __restrict__ Hdot,
                           const float* __restrict__ qv, float* __restrict__ uf_out,
                           int init_blocks) {
    int bid = blockIdx.x, tid = threadIdx.x;
    if (bid < DOT_TILES) {
        __shared__ __align__(16) float tl[DOT_VT][DOT_KC + 4];
        __shared__ __align__(16) float ufl[Bdim][DOT_KC + 4];
        int v0 = bid * DOT_VT;
        int vA = (tid >> 3) * 2, vB = vA + 1;
        int bA = (tid & 7) * 2,  bB = bA + 1;
        float aA0 = 0.f, aA1 = 0.f, aB0 = 0.f, aB1 = 0.f;
        for (int kc = 0; kc < Ddim; kc += DOT_KC) {
            __syncthreads();
#pragma unroll
            for (int i = 0; i < 4; ++i) {
                int idx = tid + i * 256;
                int r = idx >> 4, c4 = idx & 15;
                *(float4*)(&tl[r][c4 * 4]) =
                    *(const float4*)(tab + (size_t)(v0 + r) * Ddim + kc + c4 * 4);
            }
            {
                int r = tid >> 4, c4 = tid & 15;
                *(float4*)(&ufl[r][c4 * 4]) =
                    *(const float4*)(uf + (size_t)r * Ddim + kc + c4 * 4);
            }
            __syncthreads();
#pragma unroll
            for (int k4 = 0; k4 < DOT_KC / 4; ++k4) {
                const float4 a  = *(const float4*)(&tl[vA][k4 * 4]);
                const float4 c  = *(const float4*)(&tl[vB][k4 * 4]);
                const float4 u0 = *(const float4*)(&ufl[bA][k4 * 4]);
                const float4 u1 = *(const float4*)(&ufl[bB][k4 * 4]);
                aA0 += a.x*u0.x + a.y*u0.y + a.z*u0.z + a.w*u0.w;
                aA1 += a.x*u1.x + a.y*u1.y + a.z*u1.z + a.w*u1.w;
                aB0 += c.x*u0.x + c.y*u0.y + c.z*u0.z + c.w*u0.w;
                aB1 += c.x*u1.x + c.y*u1.y + c.z*u1.z + c.w*u1.w;
            }
        }
        size_t base = (size_t)(v0 + vA) * Bdim;
        D[base + bA] = aA0;  D[base + bB] = aA1;
        D[base + Bdim + bA] = aB0;  D[base + Bdim + bB] = aB1;
    } else if (bid < DOT_TILES + HD_TILES) {
        int r = bid - DOT_TILES;
        int b = r >> 4, j0 = (r & 15) * HD_JPB;
        int wave = tid >> 6, lane = tid & 63;
        const float4 u = *(const float4*)(uf + (size_t)b * Ddim + lane * 4);
        for (int j = j0 + wave; j < j0 + HD_JPB; j += 4) {
            const float4 h = *(const float4*)(hist + ((size_t)b * CONVMAX + j) * Ddim + lane * 4);
            float s = h.x*u.x + h.y*u.y + h.z*u.z + h.w*u.w;
#pragma unroll
            for (int off = 32; off > 0; off >>= 1) s += __shfl_xor(s, off, 64);
            if (lane == 0) Hdot[b * CONVMAX + j] = s;
        }
    } else {
        int b = bid - (DOT_TILES + HD_TILES);
        if (b < init_blocks)
            uf_out[(size_t)b * Ddim + tid] = qv[(size_t)b * Ddim + tid];
    }
}

// ---------------------------------------------------------------------------
// logit + per-block softmax partials (+ zero w/pwin in surplus blocks)
// grid: LG_TILES [+ ZW + PW] blocks, 256 threads
// ---------------------------------------------------------------------------
__global__ void logit_stats_kernel(const int* __restrict__ story, const int* __restrict__ kb_len,
                                   const int* __restrict__ conv_len, const float* __restrict__ D,
                                   const float* __restrict__ Hdot, const float* __restrict__ gp,
                                   float* __restrict__ lgbuf, float* __restrict__ blockmax,
                                   float* __restrict__ blocksum, float* __restrict__ w,
                                   float* __restrict__ pwin) {
    int bid = blockIdx.x, tid = threadIdx.x;
    if (bid >= LG_TILES) {
        int r = bid - LG_TILES;
        if (r < ZW_BLOCKS) {
            *(float4*)(w + (size_t)r * 1024 + tid * 4) = make_float4(0.f, 0.f, 0.f, 0.f);
        } else {
            *(float4*)(pwin + (size_t)(r - ZW_BLOCKS) * 1024 + tid * 4) = make_float4(0.f, 0.f, 0.f, 0.f);
        }
        return;
    }
    int row = bid * 256 + tid;
    int b = row >> 12, m = row & (Mdim - 1);
    const int4 st = *(const int4*)(story + (size_t)row * Tdim);
    float l = D[st.x*Bdim + b] + D[st.y*Bdim + b] + D[st.z*Bdim + b] + D[st.w*Bdim + b];
    unsigned j = (unsigned)(m - kb_len[b]);
    if (j < (unsigned)conv_len[b]) l += Hdot[b * CONVMAX + j];
    l *= gp[row];
    lgbuf[row] = l;
    __shared__ float sh[256];
    sh[tid] = l; __syncthreads();
    for (int s = 128; s > 0; s >>= 1) { if (tid < s) sh[tid] = fmaxf(sh[tid], sh[tid + s]); __syncthreads(); }
    float bm = sh[0]; __syncthreads();
    sh[tid] = expf(l - bm); __syncthreads();
    for (int s = 128; s > 0; s >>= 1) { if (tid < s) sh[tid] += sh[tid + s]; __syncthreads(); }
    if (tid == 0) { blockmax[bid] = bm; blocksum[bid] = sh[0]; }
}

// ---------------------------------------------------------------------------
// scatter: p = softmax(l)*gp; w[st[t],b] += p (x4 atomics over 640K addrs);
//          pwin for the history window.   grid: LG_TILES blocks, 256 threads
// ---------------------------------------------------------------------------
__global__ void scatter_kernel(const int* __restrict__ story, const int* __restrict__ kb_len,
                               const int* __restrict__ conv_len, const float* __restrict__ logits,
                               const float* __restrict__ blockmax, const float* __restrict__ blocksum,
                               const float* __restrict__ gp, float* __restrict__ w,
                               float* __restrict__ pwin) {
    int bid = blockIdx.x, tid = threadIdx.x;
    int b = bid >> 4;
    float M, rs;
    combine_stats(blockmax, blocksum, b, &M, &rs);
    int row = bid * 256 + tid;
    int m = row & (Mdim - 1);
    float p = expf(logits[row] - M) * rs * gp[row];
    const int4 st = *(const int4*)(story + (size_t)row * Tdim);
    atomicAdd(&w[st.x * Bdim + b], p);
    atomicAdd(&w[st.y * Bdim + b], p);
    atomicAdd(&w[st.z * Bdim + b], p);
    atomicAdd(&w[st.w * Bdim + b], p);
    unsigned j = (unsigned)(m - kb_len[b]);
    if (j < (unsigned)conv_len[b]) pwin[b * CONVMAX + j] = p;
}

// ---------------------------------------------------------------------------
// wsum: partial[b][tile][:] = sum_{v in tile} w[v,b]*tab[v,:]  (no atomics)
//       + histpart[b][c][:] over 64-j hist chunks
// grid: WS_TILES + WH_TILES = 528 blocks, 256 threads
// ---------------------------------------------------------------------------
__global__ void wsum_kernel(const float* __restrict__ tab, const float* __restrict__ w,
                            const float* __restrict__ pwin, const float* __restrict__ hist,
                            float* __restrict__ partial, float* __restrict__ histpart) {
    int bid = blockIdx.x, tid = threadIdx.x;
    if (bid < WS_TILES) {
        __shared__ float wsl[WS_VT * Bdim];
        int v0 = bid * WS_VT;
        for (int i = tid; i < WS_VT * Bdim; i += 256) wsl[i] = w[(size_t)v0 * Bdim + i];
        __syncthreads();
        int wave = tid >> 6, lane = tid & 63;
        int b0 = wave * 4, d4 = lane * 4;
        float4 a0 = make_float4(0.f,0.f,0.f,0.f), a1 = a0, a2 = a0, a3 = a0;
        for (int v = 0; v < WS_VT; ++v) {
            const float4 t = *(const float4*)(tab + (size_t)(v0 + v) * Ddim + d4);
            float w0 = wsl[v*Bdim + b0],   w1 = wsl[v*Bdim + b0+1];
            float w2 = wsl[v*Bdim + b0+2], w3 = wsl[v*Bdim + b0+3];
            a0.x += w0*t.x; a0.y += w0*t.y; a0.z += w0*t.z; a0.w += w0*t.w;
            a1.x += w1*t.x; a1.y += w1*t.y; a1.z += w1*t.z; a1.w += w1*t.w;
            a2.x += w2*t.x; a2.y += w2*t.y; a2.z += w2*t.z; a2.w += w2*t.w;
            a3.x += w3*t.x; a3.y += w3*t.y; a3.z += w3*t.z; a3.w += w3*t.w;
        }
        *(float4*)(&partial[((size_t)(b0+0) * WS_TILES + bid) * Ddim + d4]) = a0;
        *(float4*)(&partial[((size_t)(b0+1) * WS_TILES + bid) * Ddim + d4]) = a1;
        *(float4*)(&partial[((size_t)(b0+2) * WS_TILES + bid) * Ddim + d4]) = a2;
        *(float4*)(&partial[((size_t)(b0+3) * WS_TILES + bid) * Ddim + d4]) = a3;
    } else {
        int r = bid - WS_TILES;
        int b = r >> 3, c = r & 7, j0 = c * WH_JPB;
        __shared__ float sp[WH_JPB];
        if (tid < WH_JPB) sp[tid] = pwin[b * CONVMAX + j0 + tid];
        __syncthreads();
        float acc = 0.f;
        const float* hb = hist + ((size_t)b * CONVMAX + j0) * Ddim + tid;
#pragma unroll 8
        for (int j = 0; j < WH_JPB; ++j) acc += sp[j] * hb[(size_t)j * Ddim];
        histpart[((size_t)b * UF_CH + c) * Ddim + tid] = acc;
    }
}

// ---------------------------------------------------------------------------
// ufred: uf[b,:] += chunk-sums of partial + histpart   (atomic, uncontended)
// grid: Bdim * UF_CH = 128 blocks, 256 threads
// ---------------------------------------------------------------------------
__global__ void ufred_kernel(const float* __restrict__ partial, const float* __restrict__ histpart,
                             float* __restrict__ uf) {
    int b = blockIdx.x >> 3, c = blockIdx.x & 7;
    int tid = threadIdx.x;
    float acc = 0.f;
    const float* base = partial + ((size_t)b * WS_TILES + c * UF_PER) * Ddim + tid;
#pragma unroll 4
    for (int i = 0; i < UF_PER; ++i) acc += base[(size_t)i * Ddim];
    acc += histpart[((size_t)b * UF_CH + c) * Ddim + tid];
    atomicAdd(&uf[(size_t)b * Ddim + tid], acc);
}

// ---------------------------------------------------------------------------
// att: final hop — recompute e3(row) by gather; prob = softmax*gp;
//      attpart[b][ch] = sum_m prob*e3; e3 -> out_m (NT); psoft (NT).
//      Row loop fully unrolled: 16 independent row-gathers in flight.
// grid: ATT_TILES = 1024 blocks, 256 threads (wave per row)
// ---------------------------------------------------------------------------
__global__ void att_kernel(const int* __restrict__ story, const int* __restrict__ kb_len,
                           const int* __restrict__ conv_len, const float* __restrict__ hist,
                           const float* __restrict__ tab, const float* __restrict__ logits,
                           const float* __restrict__ blockmax, const float* __restrict__ blocksum,
                           const float* __restrict__ gp,
                           float* __restrict__ attpart, float* __restrict__ out_m,
                           float* __restrict__ out_psoft) {
    int bid = blockIdx.x;
    int b  = bid >> 6;                   // / ATT_CH
    int m0 = (bid & (ATT_CH - 1)) * MT;
    int tid = threadIdx.x, wave = tid >> 6, lane = tid & 63;
    int d4 = lane * 4;
    __shared__ float prob[MT];
    __shared__ float4 red[4][64];
    if (tid < MT) {
        float M, rs;
        combine_stats(blockmax, blocksum, b, &M, &rs);
        size_t row = (size_t)b * Mdim + m0 + tid;
        float pn = expf(logits[row] - M) * rs;
        nt_store1(out_psoft + row, pn);
        prob[tid] = pn * gp[row];
    }
    __syncthreads();
    int kb = kb_len[b], cl = conv_len[b];
    float4 acc = make_float4(0.f, 0.f, 0.f, 0.f);
#pragma unroll
    for (int mm = wave; mm < MT; mm += 4) {
        int m = m0 + mm;
        size_t row = (size_t)b * Mdim + m;
        const int* st = story + row * Tdim;
        float4 v = make_float4(0.f, 0.f, 0.f, 0.f);
#pragma unroll
        for (int t = 0; t < Tdim; ++t) {
            const float4 wv = *(const float4*)(tab + (size_t)st[t] * Ddim + d4);
            v.x += wv.x; v.y += wv.y; v.z += wv.z; v.w += wv.w;
        }
        if (m >= kb && m < kb + cl) {
            const float4 h = *(const float4*)(hist + ((size_t)b * CONVMAX + (m - kb)) * Ddim + d4);
            v.x += h.x; v.y += h.y; v.z += h.z; v.w += h.w;
        }
        nt_store4(out_m + row * Ddim + d4, v);
        float p = prob[mm];
        acc.x += p * v.x; acc.y += p * v.y; acc.z += p * v.z; acc.w += p * v.w;
    }
    red[wave][lane] = acc;
    __syncthreads();
    if (wave == 0) {
        float4 a0 = red[0][lane], a1 = red[1][lane], a2 = red[2][lane], a3 = red[3][lane];
        float4 t4;
        t4.x = a0.x + a1.x + a2.x + a3.x;
        t4.y = a0.y + a1.y + a2.y + a3.y;
        t4.z = a0.z + a1.z + a2.z + a3.z;
        t4.w = a0.w + a1.w + a2.w + a3.w;
        *(float4*)(&attpart[((size_t)b * ATT_CH + (bid & (ATT_CH - 1))) * Ddim + d4]) = t4;
    }
}

// ---------------------------------------------------------------------------
// attred: uf[b,:] += chunk-sums of attpart   grid: Bdim*4 = 64 blocks
// ---------------------------------------------------------------------------
__global__ void attred_kernel(const float* __restrict__ attpart, float* __restrict__ uf) {
    int b = blockIdx.x >> 2, c = blockIdx.x & 3;
    int tid = threadIdx.x;
    float acc = 0.f;
    const float* base = attpart + ((size_t)b * ATT_CH + c * 16) * Ddim + tid;
#pragma unroll 4
    for (int i = 0; i < 16; ++i) acc += base[(size_t)i * Ddim];
    atomicAdd(&uf[(size_t)b * Ddim + tid], acc);
}

extern "C" void kernel_launch(void* const* d_in, const int* in_sizes, int n_in,
                              void* d_out, int out_size, void* d_ws, size_t ws_size,
                              hipStream_t stream) {
    const int*   story        = (const int*)d_in[0];
    const int*   kb_len       = (const int*)d_in[1];
    const int*   conv_len     = (const int*)d_in[2];
    // d_in[3] (query), d_in[8..11] (Tg_w, Tg_b, FW_w, FW_b): dead w.r.t. outputs
    const float* hist         = (const float*)d_in[4];
    const float* query_vector = (const float*)d_in[5];
    const float* gp           = (const float*)d_in[6];
    const float* C_emb        = (const float*)d_in[7];

    float* out        = (float*)d_out;
    float* out_psoft  = out;                                   // B*M
    float* out_logits = out + (size_t)Bdim * Mdim;             // B*M
    float* out_uf     = out + 2 * (size_t)Bdim * Mdim;         // B*D
    float* out_m      = out + 2 * (size_t)Bdim * Mdim + (size_t)Bdim * Ddim; // B*M*D

    float* wsp = (float*)d_ws;
    float* D        = wsp;                                     // V*B
    float* w        = D + (size_t)Vdim * Bdim;                 // V*B
    float* Hdot     = w + (size_t)Vdim * Bdim;                 // B*CONVMAX
    float* pwin     = Hdot + (size_t)Bdim * CONVMAX;           // B*CONVMAX
    float* logits   = pwin + (size_t)Bdim * CONVMAX;           // B*M
    float* blockmax = logits + (size_t)Bdim * Mdim;            // 256
    float* blocksum = blockmax + 256;                          // 256
    float* partial  = blocksum + 256;                          // B*400*D
    float* histpart = partial + (size_t)Bdim * WS_TILES * Ddim; // B*8*D
    float* attpart  = histpart + (size_t)Bdim * UF_CH * Ddim;  // B*64*D

    const size_t TAB = (size_t)Vdim * Ddim;
    const float* tab[4] = { C_emb, C_emb + TAB, C_emb + 2*TAB, C_emb + 3*TAB };

    for (int h = 0; h < 2; ++h) {
        const float* ufsrc = (h == 0) ? query_vector : out_uf;
        int initb = (h == 0) ? Bdim : 0;
        dot_kernel<<<DOT_TILES + HD_TILES + initb, 256, 0, stream>>>(
            tab[h], ufsrc, hist, D, Hdot, query_vector, out_uf, initb);
        logit_stats_kernel<<<LG_TILES + ZW_BLOCKS + PW_BLOCKS, 256, 0, stream>>>(
            story, kb_len, conv_len, D, Hdot, gp, logits, blockmax, blocksum, w, pwin);
        scatter_kernel<<<LG_TILES, 256, 0, stream>>>(story, kb_len, conv_len, logits,
                                                     blockmax, blocksum, gp, w, pwin);
        wsum_kernel<<<WS_TILES + WH_TILES, 256, 0, stream>>>(tab[h + 1], w, pwin, hist,
                                                             partial, histpart);
        ufred_kernel<<<Bdim * UF_CH, 256, 0, stream>>>(partial, histpart, out_uf);
    }

    // hop 2: logits/psoft are outputs; out_m forces the one real gather pass
    dot_kernel<<<DOT_TILES + HD_TILES, 256, 0, stream>>>(
        tab[2], out_uf, hist, D, Hdot, query_vector, out_uf, 0);
    logit_stats_kernel<<<LG_TILES, 256, 0, stream>>>(
        story, kb_len, conv_len, D, Hdot, gp, out_logits, blockmax, blocksum,
        (float*)nullptr, (float*)nullptr);
    att_kernel<<<ATT_TILES, 256, 0, stream>>>(story, kb_len, conv_len, hist, tab[3],
                                              out_logits, blockmax, blocksum, gp,
                                              attpart, out_m, out_psoft);
    attred_kernel<<<Bdim * 4, 256, 0, stream>>>(attpart, out_uf);
}

// Round 12
// 415.892 us; speedup vs baseline: 1.0097x; 1.0097x over previous
//
#include <hip/hip_runtime.h>
#include <math.h>

#define Bdim 16
#define Mdim 4096
#define Tdim 4
#define Ddim 256
#define Vdim 40000
#define CONVMAX 512

// dot (D = tab . uf) tiling
#define DOT_VT 64
#define DOT_TILES (Vdim / DOT_VT)               // 625
#define DOT_KC 64
#define HD_JPB 32
#define HD_TILES (Bdim * (CONVMAX / HD_JPB))    // 256
// logit tiling
#define LG_TILES (Bdim * Mdim / 256)            // 256  (16 per b)
#define ZW_BLOCKS (Vdim * Bdim / 1024)          // 625
#define PW_BLOCKS (Bdim * CONVMAX / 1024)       // 8
// wsum tiling
#define WS_VT 50
#define WS_TILES (Vdim / WS_VT)                 // 800
#define WH_JPB 64
#define WH_TILES (Bdim * (CONVMAX / WH_JPB))    // 128
// reduce tiling
#define UF_CH 8
#define UF_PER (WS_TILES / UF_CH)               // 100
// att tiling
#define MT 32
#define ATT_CH (Mdim / MT)                      // 128
#define ATT_TILES (Bdim * ATT_CH)               // 2048

typedef float f32x4 __attribute__((ext_vector_type(4)));
static __device__ inline void nt_store4(float* p, float4 v) {
    f32x4 x = {v.x, v.y, v.z, v.w};
    __builtin_nontemporal_store(x, (f32x4*)p);
}
static __device__ inline void nt_store1(float* p, float v) {
    __builtin_nontemporal_store(v, p);
}

// combine per-b softmax partials (16 blocks of 256 rows each)
static __device__ inline void combine_stats(const float* __restrict__ blockmax,
                                            const float* __restrict__ blocksum,
                                            int b, float* M_out, float* rs_out) {
    float M = -INFINITY;
#pragma unroll
    for (int jj = 0; jj < 16; ++jj) M = fmaxf(M, blockmax[b * 16 + jj]);
    float S = 0.f;
#pragma unroll
    for (int jj = 0; jj < 16; ++jj) S += blocksum[b * 16 + jj] * expf(blockmax[b * 16 + jj] - M);
    *M_out = M;
    *rs_out = 1.0f / S;
}

// ---------------------------------------------------------------------------
// dot: D[v*16+b] = tab[v,:].uf[b,:]  (GEMM microtile) + Hdot
//      [+ init blocks: uf_out = qv, folded into the dot0 launch]
// grid: DOT_TILES + HD_TILES [+ init] blocks, 256 threads
// ---------------------------------------------------------------------------
__global__ void dot_kernel(const float* __restrict__ tab, const float* __restrict__ uf,
                           const float* __restrict__ hist,
                           float* __restrict__ D, float* __restrict__ Hdot,
                           const float* __restrict__ qv, float* __restrict__ uf_out,
                           int init_blocks) {
    int bid = blockIdx.x, tid = threadIdx.x;
    if (bid < DOT_TILES) {
        __shared__ __align__(16) float tl[DOT_VT][DOT_KC + 4];
        __shared__ __align__(16) float ufl[Bdim][DOT_KC + 4];
        int v0 = bid * DOT_VT;
        int vA = (tid >> 3) * 2, vB = vA + 1;
        int bA = (tid & 7) * 2,  bB = bA + 1;
        float aA0 = 0.f, aA1 = 0.f, aB0 = 0.f, aB1 = 0.f;
        for (int kc = 0; kc < Ddim; kc += DOT_KC) {
            __syncthreads();
#pragma unroll
            for (int i = 0; i < 4; ++i) {
                int idx = tid + i * 256;
                int r = idx >> 4, c4 = idx & 15;
                *(float4*)(&tl[r][c4 * 4]) =
                    *(const float4*)(tab + (size_t)(v0 + r) * Ddim + kc + c4 * 4);
            }
            {
                int r = tid >> 4, c4 = tid & 15;
                *(float4*)(&ufl[r][c4 * 4]) =
                    *(const float4*)(uf + (size_t)r * Ddim + kc + c4 * 4);
            }
            __syncthreads();
#pragma unroll
            for (int k4 = 0; k4 < DOT_KC / 4; ++k4) {
                const float4 a  = *(const float4*)(&tl[vA][k4 * 4]);
                const float4 c  = *(const float4*)(&tl[vB][k4 * 4]);
                const float4 u0 = *(const float4*)(&ufl[bA][k4 * 4]);
                const float4 u1 = *(const float4*)(&ufl[bB][k4 * 4]);
                aA0 += a.x*u0.x + a.y*u0.y + a.z*u0.z + a.w*u0.w;
                aA1 += a.x*u1.x + a.y*u1.y + a.z*u1.z + a.w*u1.w;
                aB0 += c.x*u0.x + c.y*u0.y + c.z*u0.z + c.w*u0.w;
                aB1 += c.x*u1.x + c.y*u1.y + c.z*u1.z + c.w*u1.w;
            }
        }
        size_t base = (size_t)(v0 + vA) * Bdim;
        D[base + bA] = aA0;  D[base + bB] = aA1;
        D[base + Bdim + bA] = aB0;  D[base + Bdim + bB] = aB1;
    } else if (bid < DOT_TILES + HD_TILES) {
        int r = bid - DOT_TILES;
        int b = r >> 4, j0 = (r & 15) * HD_JPB;
        int wave = tid >> 6, lane = tid & 63;
        const float4 u = *(const float4*)(uf + (size_t)b * Ddim + lane * 4);
        for (int j = j0 + wave; j < j0 + HD_JPB; j += 4) {
            const float4 h = *(const float4*)(hist + ((size_t)b * CONVMAX + j) * Ddim + lane * 4);
            float s = h.x*u.x + h.y*u.y + h.z*u.z + h.w*u.w;
#pragma unroll
            for (int off = 32; off > 0; off >>= 1) s += __shfl_xor(s, off, 64);
            if (lane == 0) Hdot[b * CONVMAX + j] = s;
        }
    } else {
        int b = bid - (DOT_TILES + HD_TILES);
        if (b < init_blocks)
            uf_out[(size_t)b * Ddim + tid] = qv[(size_t)b * Ddim + tid];
    }
}

// ---------------------------------------------------------------------------
// logit + per-block softmax partials (+ zero w/pwin in surplus blocks)
// grid: LG_TILES [+ ZW + PW] blocks, 256 threads
// ---------------------------------------------------------------------------
__global__ void logit_stats_kernel(const int* __restrict__ story, const int* __restrict__ kb_len,
                                   const int* __restrict__ conv_len, const float* __restrict__ D,
                                   const float* __restrict__ Hdot, const float* __restrict__ gp,
                                   float* __restrict__ lgbuf, float* __restrict__ blockmax,
                                   float* __restrict__ blocksum, float* __restrict__ w,
                                   float* __restrict__ pwin) {
    int bid = blockIdx.x, tid = threadIdx.x;
    if (bid >= LG_TILES) {
        int r = bid - LG_TILES;
        if (r < ZW_BLOCKS) {
            *(float4*)(w + (size_t)r * 1024 + tid * 4) = make_float4(0.f, 0.f, 0.f, 0.f);
        } else {
            *(float4*)(pwin + (size_t)(r - ZW_BLOCKS) * 1024 + tid * 4) = make_float4(0.f, 0.f, 0.f, 0.f);
        }
        return;
    }
    int row = bid * 256 + tid;
    int b = row >> 12, m = row & (Mdim - 1);
    const int4 st = *(const int4*)(story + (size_t)row * Tdim);
    float l = D[st.x*Bdim + b] + D[st.y*Bdim + b] + D[st.z*Bdim + b] + D[st.w*Bdim + b];
    unsigned j = (unsigned)(m - kb_len[b]);
    if (j < (unsigned)conv_len[b]) l += Hdot[b * CONVMAX + j];
    l *= gp[row];
    lgbuf[row] = l;
    __shared__ float sh[256];
    sh[tid] = l; __syncthreads();
    for (int s = 128; s > 0; s >>= 1) { if (tid < s) sh[tid] = fmaxf(sh[tid], sh[tid + s]); __syncthreads(); }
    float bm = sh[0]; __syncthreads();
    sh[tid] = expf(l - bm); __syncthreads();
    for (int s = 128; s > 0; s >>= 1) { if (tid < s) sh[tid] += sh[tid + s]; __syncthreads(); }
    if (tid == 0) { blockmax[bid] = bm; blocksum[bid] = sh[0]; }
}

// ---------------------------------------------------------------------------
// scatter: p = softmax(l)*gp; w[st[t],b] += p (x4 atomics over 640K addrs);
//          pwin for the history window.   grid: LG_TILES blocks, 256 threads
// ---------------------------------------------------------------------------
__global__ void scatter_kernel(const int* __restrict__ story, const int* __restrict__ kb_len,
                               const int* __restrict__ conv_len, const float* __restrict__ logits,
                               const float* __restrict__ blockmax, const float* __restrict__ blocksum,
                               const float* __restrict__ gp, float* __restrict__ w,
                               float* __restrict__ pwin) {
    int bid = blockIdx.x, tid = threadIdx.x;
    int b = bid >> 4;
    float M, rs;
    combine_stats(blockmax, blocksum, b, &M, &rs);
    int row = bid * 256 + tid;
    int m = row & (Mdim - 1);
    float p = expf(logits[row] - M) * rs * gp[row];
    const int4 st = *(const int4*)(story + (size_t)row * Tdim);
    atomicAdd(&w[st.x * Bdim + b], p);
    atomicAdd(&w[st.y * Bdim + b], p);
    atomicAdd(&w[st.z * Bdim + b], p);
    atomicAdd(&w[st.w * Bdim + b], p);
    unsigned j = (unsigned)(m - kb_len[b]);
    if (j < (unsigned)conv_len[b]) pwin[b * CONVMAX + j] = p;
}

// ---------------------------------------------------------------------------
// wsum: partial[b][tile][:] = sum_{v in tile} w[v,b]*tab[v,:]  (no atomics)
//       + histpart[b][c][:] over 64-j hist chunks
// grid: WS_TILES + WH_TILES = 928 blocks, 256 threads
// ---------------------------------------------------------------------------
__global__ void wsum_kernel(const float* __restrict__ tab, const float* __restrict__ w,
                            const float* __restrict__ pwin, const float* __restrict__ hist,
                            float* __restrict__ partial, float* __restrict__ histpart) {
    int bid = blockIdx.x, tid = threadIdx.x;
    if (bid < WS_TILES) {
        __shared__ float wsl[WS_VT * Bdim];
        int v0 = bid * WS_VT;
        for (int i = tid; i < WS_VT * Bdim; i += 256) wsl[i] = w[(size_t)v0 * Bdim + i];
        __syncthreads();
        int wave = tid >> 6, lane = tid & 63;
        int b0 = wave * 4, d4 = lane * 4;
        float4 a0 = make_float4(0.f,0.f,0.f,0.f), a1 = a0, a2 = a0, a3 = a0;
        for (int v = 0; v < WS_VT; ++v) {
            const float4 t = *(const float4*)(tab + (size_t)(v0 + v) * Ddim + d4);
            float w0 = wsl[v*Bdim + b0],   w1 = wsl[v*Bdim + b0+1];
            float w2 = wsl[v*Bdim + b0+2], w3 = wsl[v*Bdim + b0+3];
            a0.x += w0*t.x; a0.y += w0*t.y; a0.z += w0*t.z; a0.w += w0*t.w;
            a1.x += w1*t.x; a1.y += w1*t.y; a1.z += w1*t.z; a1.w += w1*t.w;
            a2.x += w2*t.x; a2.y += w2*t.y; a2.z += w2*t.z; a2.w += w2*t.w;
            a3.x += w3*t.x; a3.y += w3*t.y; a3.z += w3*t.z; a3.w += w3*t.w;
        }
        *(float4*)(&partial[((size_t)(b0+0) * WS_TILES + bid) * Ddim + d4]) = a0;
        *(float4*)(&partial[((size_t)(b0+1) * WS_TILES + bid) * Ddim + d4]) = a1;
        *(float4*)(&partial[((size_t)(b0+2) * WS_TILES + bid) * Ddim + d4]) = a2;
        *(float4*)(&partial[((size_t)(b0+3) * WS_TILES + bid) * Ddim + d4]) = a3;
    } else {
        int r = bid - WS_TILES;
        int b = r >> 3, c = r & 7, j0 = c * WH_JPB;
        __shared__ float sp[WH_JPB];
        if (tid < WH_JPB) sp[tid] = pwin[b * CONVMAX + j0 + tid];
        __syncthreads();
        float acc = 0.f;
        const float* hb = hist + ((size_t)b * CONVMAX + j0) * Ddim + tid;
#pragma unroll 8
        for (int j = 0; j < WH_JPB; ++j) acc += sp[j] * hb[(size_t)j * Ddim];
        histpart[((size_t)b * UF_CH + c) * Ddim + tid] = acc;
    }
}

// ---------------------------------------------------------------------------
// ufred: uf[b,:] += chunk-sums of partial + histpart   (atomic, uncontended)
// grid: Bdim * UF_CH = 128 blocks, 256 threads
// ---------------------------------------------------------------------------
__global__ void ufred_kernel(const float* __restrict__ partial, const float* __restrict__ histpart,
                             float* __restrict__ uf) {
    int b = blockIdx.x >> 3, c = blockIdx.x & 7;
    int tid = threadIdx.x;
    float acc = 0.f;
    const float* base = partial + ((size_t)b * WS_TILES + c * UF_PER) * Ddim + tid;
#pragma unroll 4
    for (int i = 0; i < UF_PER; ++i) acc += base[(size_t)i * Ddim];
    acc += histpart[((size_t)b * UF_CH + c) * Ddim + tid];
    atomicAdd(&uf[(size_t)b * Ddim + tid], acc);
}

// ---------------------------------------------------------------------------
// att: final hop — recompute e3(row) by gather; prob = softmax*gp;
//      attpart[b][ch] = sum_m prob*e3; e3 -> out_m (NT); psoft (NT).
//      Row loop fully unrolled: 8 independent row-gathers in flight.
// grid: ATT_TILES = 2048 blocks, 256 threads (wave per row)
// ---------------------------------------------------------------------------
__global__ void att_kernel(const int* __restrict__ story, const int* __restrict__ kb_len,
                           const int* __restrict__ conv_len, const float* __restrict__ hist,
                           const float* __restrict__ tab, const float* __restrict__ logits,
                           const float* __restrict__ blockmax, const float* __restrict__ blocksum,
                           const float* __restrict__ gp,
                           float* __restrict__ attpart, float* __restrict__ out_m,
                           float* __restrict__ out_psoft) {
    int bid = blockIdx.x;
    int b  = bid >> 7;                   // / ATT_CH
    int m0 = (bid & (ATT_CH - 1)) * MT;
    int tid = threadIdx.x, wave = tid >> 6, lane = tid & 63;
    int d4 = lane * 4;
    __shared__ float prob[MT];
    __shared__ float4 red[4][64];
    if (tid < MT) {
        float M, rs;
        combine_stats(blockmax, blocksum, b, &M, &rs);
        size_t row = (size_t)b * Mdim + m0 + tid;
        float pn = expf(logits[row] - M) * rs;
        nt_store1(out_psoft + row, pn);
        prob[tid] = pn * gp[row];
    }
    __syncthreads();
    int kb = kb_len[b], cl = conv_len[b];
    float4 acc = make_float4(0.f, 0.f, 0.f, 0.f);
#pragma unroll
    for (int mm = wave; mm < MT; mm += 4) {
        int m = m0 + mm;
        size_t row = (size_t)b * Mdim + m;
        const int* st = story + row * Tdim;
        float4 v = make_float4(0.f, 0.f, 0.f, 0.f);
#pragma unroll
        for (int t = 0; t < Tdim; ++t) {
            const float4 wv = *(const float4*)(tab + (size_t)st[t] * Ddim + d4);
            v.x += wv.x; v.y += wv.y; v.z += wv.z; v.w += wv.w;
        }
        if (m >= kb && m < kb + cl) {
            const float4 h = *(const float4*)(hist + ((size_t)b * CONVMAX + (m - kb)) * Ddim + d4);
            v.x += h.x; v.y += h.y; v.z += h.z; v.w += h.w;
        }
        nt_store4(out_m + row * Ddim + d4, v);
        float p = prob[mm];
        acc.x += p * v.x; acc.y += p * v.y; acc.z += p * v.z; acc.w += p * v.w;
    }
    red[wave][lane] = acc;
    __syncthreads();
    if (wave == 0) {
        float4 a0 = red[0][lane], a1 = red[1][lane], a2 = red[2][lane], a3 = red[3][lane];
        float4 t4;
        t4.x = a0.x + a1.x + a2.x + a3.x;
        t4.y = a0.y + a1.y + a2.y + a3.y;
        t4.z = a0.z + a1.z + a2.z + a3.z;
        t4.w = a0.w + a1.w + a2.w + a3.w;
        *(float4*)(&attpart[((size_t)b * ATT_CH + (bid & (ATT_CH - 1))) * Ddim + d4]) = t4;
    }
}

// ---------------------------------------------------------------------------
// attred: uf[b,:] += chunk-sums of attpart   grid: Bdim*4 = 64 blocks
// ---------------------------------------------------------------------------
__global__ void attred_kernel(const float* __restrict__ attpart, float* __restrict__ uf) {
    int b = blockIdx.x >> 2, c = blockIdx.x & 3;
    int tid = threadIdx.x;
    float acc = 0.f;
    const float* base = attpart + ((size_t)b * ATT_CH + c * 32) * Ddim + tid;
#pragma unroll 4
    for (int i = 0; i < 32; ++i) acc += base[(size_t)i * Ddim];
    atomicAdd(&uf[(size_t)b * Ddim + tid], acc);
}

extern "C" void kernel_launch(void* const* d_in, const int* in_sizes, int n_in,
                              void* d_out, int out_size, void* d_ws, size_t ws_size,
                              hipStream_t stream) {
    const int*   story        = (const int*)d_in[0];
    const int*   kb_len       = (const int*)d_in[1];
    const int*   conv_len     = (const int*)d_in[2];
    // d_in[3] (query), d_in[8..11] (Tg_w, Tg_b, FW_w, FW_b): dead w.r.t. outputs
    const float* hist         = (const float*)d_in[4];
    const float* query_vector = (const float*)d_in[5];
    const float* gp           = (const float*)d_in[6];
    const float* C_emb        = (const float*)d_in[7];

    float* out        = (float*)d_out;
    float* out_psoft  = out;                                   // B*M
    float* out_logits = out + (size_t)Bdim * Mdim;             // B*M
    float* out_uf     = out + 2 * (size_t)Bdim * Mdim;         // B*D
    float* out_m      = out + 2 * (size_t)Bdim * Mdim + (size_t)Bdim * Ddim; // B*M*D

    float* wsp = (float*)d_ws;
    float* D        = wsp;                                     // V*B
    float* w        = D + (size_t)Vdim * Bdim;                 // V*B
    float* Hdot     = w + (size_t)Vdim * Bdim;                 // B*CONVMAX
    float* pwin     = Hdot + (size_t)Bdim * CONVMAX;           // B*CONVMAX
    float* logits   = pwin + (size_t)Bdim * CONVMAX;           // B*M
    float* blockmax = logits + (size_t)Bdim * Mdim;            // 256
    float* blocksum = blockmax + 256;                          // 256
    float* partial  = blocksum + 256;                          // B*800*D
    float* histpart = partial + (size_t)Bdim * WS_TILES * Ddim; // B*8*D
    float* attpart  = histpart + (size_t)Bdim * UF_CH * Ddim;  // B*128*D

    const size_t TAB = (size_t)Vdim * Ddim;
    const float* tab[4] = { C_emb, C_emb + TAB, C_emb + 2*TAB, C_emb + 3*TAB };

    for (int h = 0; h < 2; ++h) {
        const float* ufsrc = (h == 0) ? query_vector : out_uf;
        int initb = (h == 0) ? Bdim : 0;
        dot_kernel<<<DOT_TILES + HD_TILES + initb, 256, 0, stream>>>(
            tab[h], ufsrc, hist, D, Hdot, query_vector, out_uf, initb);
        logit_stats_kernel<<<LG_TILES + ZW_BLOCKS + PW_BLOCKS, 256, 0, stream>>>(
            story, kb_len, conv_len, D, Hdot, gp, logits, blockmax, blocksum, w, pwin);
        scatter_kernel<<<LG_TILES, 256, 0, stream>>>(story, kb_len, conv_len, logits,
                                                     blockmax, blocksum, gp, w, pwin);
        wsum_kernel<<<WS_TILES + WH_TILES, 256, 0, stream>>>(tab[h + 1], w, pwin, hist,
                                                             partial, histpart);
        ufred_kernel<<<Bdim * UF_CH, 256, 0, stream>>>(partial, histpart, out_uf);
    }

    // hop 2: logits/psoft are outputs; out_m forces the one real gather pass
    dot_kernel<<<DOT_TILES + HD_TILES, 256, 0, stream>>>(
        tab[2], out_uf, hist, D, Hdot, query_vector, out_uf, 0);
    logit_stats_kernel<<<LG_TILES, 256, 0, stream>>>(
        story, kb_len, conv_len, D, Hdot, gp, out_logits, blockmax, blocksum,
        (float*)nullptr, (float*)nullptr);
    att_kernel<<<ATT_TILES, 256, 0, stream>>>(story, kb_len, conv_len, hist, tab[3],
                                              out_logits, blockmax, blocksum, gp,
                                              attpart, out_m, out_psoft);
    attred_kernel<<<Bdim * 4, 256, 0, stream>>>(attpart, out_uf);
}